// Round 3
// baseline (7507.643 us; speedup 1.0000x reference)
//
#include <hip/hip_runtime.h>
#include <hip/hip_bf16.h>

// GRU B=64 T=1024 D=U=512, reset_after=true. fp32 in/out, bf16 MFMA internally.
//
// ws layout (bytes):
//   [0,128)                  flags[32]  (one 128B line; memset each launch)
//   [4096, +131072)          h broadcast, bf16, double buffered [2][64][512]
//   [135168, +1572864)       Wt  bf16 [1536][512]  (kernel^T)
//   [1708032, +1572864)      Rt  bf16 [1536][512]  (recurrent_kernel^T)
//   [3280896, +201326592)    XM  bf16 [T*64][1536] (x@W + b_i), row = t*64+b

typedef __attribute__((ext_vector_type(8))) short short8;
typedef __attribute__((ext_vector_type(4))) float f32x4;

__device__ __forceinline__ unsigned short f2bf(float f) {
  unsigned u = __float_as_uint(f);
  u += 0x7FFFu + ((u >> 16) & 1u);   // RNE
  return (unsigned short)(u >> 16);
}
__device__ __forceinline__ float bf2f(unsigned short s) {
  return __uint_as_float(((unsigned)s) << 16);
}

// ---------------- Phase 0: transpose fp32 [R][C] -> bf16 [C][R] ----------------
__global__ void transpose_cast(const float* __restrict__ src,
                               unsigned short* __restrict__ dst,
                               int R, int C) {
  __shared__ float tile[32][33];
  int c0 = blockIdx.x * 32, r0 = blockIdx.y * 32;
  int tx = threadIdx.x, ty = threadIdx.y;
#pragma unroll
  for (int i = 0; i < 4; i++) {
    tile[ty + i * 8][tx] = src[(size_t)(r0 + ty + i * 8) * C + c0 + tx];
  }
  __syncthreads();
#pragma unroll
  for (int i = 0; i < 4; i++) {
    dst[(size_t)(c0 + ty + i * 8) * R + r0 + tx] = f2bf(tile[tx][ty + i * 8]);
  }
}

// ---------------- Phase 1: XM = x @ W + b_i  (bf16 out) ----------------
// M=65536 (row = t*64+b), N=1536, K=512. Tiles 128x128x64, 4 waves.
__global__ __launch_bounds__(256) void xm_gemm(const float* __restrict__ x,
                                               const unsigned short* __restrict__ Wt,
                                               const float* __restrict__ bias,
                                               unsigned short* __restrict__ XM) {
  __shared__ unsigned short As[128][72];
  __shared__ unsigned short Bs[128][72];
  const int tid = threadIdx.x;
  const int bm = blockIdx.x;   // 512
  const int bn = blockIdx.y;   // 12
  const int wave = tid >> 6, lane = tid & 63;
  const int moff = (wave & 1) * 64, noff = (wave >> 1) * 64;

  f32x4 acc[4][4];
#pragma unroll
  for (int mt = 0; mt < 4; mt++)
#pragma unroll
    for (int nt = 0; nt < 4; nt++) acc[mt][nt] = (f32x4){0.f, 0.f, 0.f, 0.f};

  const int r = tid >> 1;
  const int kb = (tid & 1) * 32;
  const int rg = bm * 128 + r;
  const int bb = rg & 63, tt = rg >> 6;

  for (int k0 = 0; k0 < 512; k0 += 64) {
    // A fill: 128 rows x 64 k fp32 -> bf16
    const f32x4* xp4 = (const f32x4*)(x + ((size_t)bb * 1024 + tt) * 512 + k0 + kb);
#pragma unroll
    for (int j = 0; j < 4; j++) {
      f32x4 lo = xp4[2 * j];
      f32x4 hi = xp4[2 * j + 1];
      union { unsigned short us[8]; short8 v; } u;
      u.us[0] = f2bf(lo[0]); u.us[1] = f2bf(lo[1]); u.us[2] = f2bf(lo[2]); u.us[3] = f2bf(lo[3]);
      u.us[4] = f2bf(hi[0]); u.us[5] = f2bf(hi[1]); u.us[6] = f2bf(hi[2]); u.us[7] = f2bf(hi[3]);
      *(short8*)&As[r][kb + j * 8] = u.v;
    }
    // B fill: Wt rows n, k-contiguous bf16
    const short8* wp8 = (const short8*)(Wt + (size_t)(bn * 128 + r) * 512 + k0 + kb);
#pragma unroll
    for (int j = 0; j < 4; j++) *(short8*)&Bs[r][kb + j * 8] = wp8[j];
    __syncthreads();

#pragma unroll
    for (int kk = 0; kk < 2; kk++) {
      short8 a[4], b[4];
#pragma unroll
      for (int mt = 0; mt < 4; mt++)
        a[mt] = *(const short8*)&As[moff + mt * 16 + (lane & 15)][kk * 32 + (lane >> 4) * 8];
#pragma unroll
      for (int nt = 0; nt < 4; nt++)
        b[nt] = *(const short8*)&Bs[noff + nt * 16 + (lane & 15)][kk * 32 + (lane >> 4) * 8];
#pragma unroll
      for (int mt = 0; mt < 4; mt++)
#pragma unroll
        for (int nt = 0; nt < 4; nt++)
          acc[mt][nt] = __builtin_amdgcn_mfma_f32_16x16x32_bf16(a[mt], b[nt], acc[mt][nt], 0, 0, 0);
    }
    __syncthreads();
  }

#pragma unroll
  for (int nt = 0; nt < 4; nt++) {
    const int cg = bn * 128 + noff + nt * 16 + (lane & 15);
    const float bi = bias[cg];
#pragma unroll
    for (int mt = 0; mt < 4; mt++) {
      const int rg2 = bm * 128 + moff + mt * 16 + (lane >> 4) * 4;
#pragma unroll
      for (int i = 0; i < 4; i++)
        XM[(size_t)(rg2 + i) * 1536 + cg] = f2bf(acc[mt][nt][i] + bi);
    }
  }
}

// ---------------- Phase 2: sequential recurrence, persistent grid ----------------
// 32 blocks x 256 threads. Block owns 16 units (48 R^T rows in VGPRs).
// h broadcast: double-buffered global bf16, relaxed agent atomics (MALL).
// Rendezvous: per-block flags in ONE 128B line; parallel arrival stores,
// single-vector-load polling. flags[blk] = t+1 means block blk finished step t.
__global__ __launch_bounds__(256, 1) void gru_rec(const unsigned short* __restrict__ Rt,
                                                  const unsigned short* __restrict__ XM,
                                                  const float* __restrict__ bias,
                                                  unsigned short* h_bf,
                                                  unsigned int* flags,
                                                  float* __restrict__ out) {
  const int tid = threadIdx.x;
  const int lane = tid & 63;
  const int wave = tid >> 6;          // 0..3 -> batches wave*16..+15
  const int blk = blockIdx.x;         // 0..31 -> units blk*16..+15
  const int u0 = blk * 16;
  const int col = lane & 15;
  const int krow = lane >> 4;         // 0..3

  // B fragments: Rt[g*512+u0+col][k], k = ks*32 + krow*8 + j
  short8 Bf[3][16];
#pragma unroll
  for (int g = 0; g < 3; g++)
#pragma unroll
    for (int ks = 0; ks < 16; ks++)
      Bf[g][ks] = *(const short8*)(Rt + (size_t)(g * 512 + u0 + col) * 512 + ks * 32 + krow * 8);

  const float br0 = bias[1536 + 0 * 512 + u0 + col];
  const float br1 = bias[1536 + 1 * 512 + u0 + col];
  const float br2 = bias[1536 + 2 * 512 + u0 + col];

  float hreg[4] = {0.f, 0.f, 0.f, 0.f};   // own (batch,unit) state, fp32

  unsigned short xc[3][4], xn[3][4];
#pragma unroll
  for (int g = 0; g < 3; g++)
#pragma unroll
    for (int i = 0; i < 4; i++) {
      int batch = wave * 16 + krow * 4 + i;
      xc[g][i] = XM[(size_t)batch * 1536 + g * 512 + u0 + col];
    }

#pragma unroll 1
  for (int t = 0; t < 1024; ++t) {
    // prefetch next step's XM gate inputs (hidden under poll + MFMA)
    const int tn = (t < 1023) ? t + 1 : 1023;
#pragma unroll
    for (int g = 0; g < 3; g++)
#pragma unroll
      for (int i = 0; i < 4; i++) {
        int batch = wave * 16 + krow * 4 + i;
        xn[g][i] = XM[(size_t)(tn * 64 + batch) * 1536 + g * 512 + u0 + col];
      }

    f32x4 acc0 = (f32x4){0.f, 0.f, 0.f, 0.f};
    f32x4 acc1 = acc0, acc2 = acc0;

    if (t > 0) {
      // wait until every block has published step t-1 (flags[i] >= t).
      // one 128B-line vector load per poll; each wave polls independently.
      const unsigned tgt = (unsigned)t;
      for (;;) {
        unsigned v = (lane < 32)
            ? __hip_atomic_load(&flags[lane], __ATOMIC_RELAXED, __HIP_MEMORY_SCOPE_AGENT)
            : tgt;
        if (__all((int)(v >= tgt))) break;
        __builtin_amdgcn_s_sleep(1);
      }

      const unsigned short* hb = h_bf + ((t + 1) & 1) * (64 * 512);  // state from t-1
      const unsigned short* hp = hb + (size_t)(wave * 16 + col) * 512 + krow * 8;
      short8 Af[16];
#pragma unroll
      for (int ks = 0; ks < 16; ks++) {
        union { unsigned long long q[2]; short8 v; } u;
        const unsigned long long* p = (const unsigned long long*)(hp + ks * 32);
        u.q[0] = __hip_atomic_load(p, __ATOMIC_RELAXED, __HIP_MEMORY_SCOPE_AGENT);
        u.q[1] = __hip_atomic_load(p + 1, __ATOMIC_RELAXED, __HIP_MEMORY_SCOPE_AGENT);
        Af[ks] = u.v;
      }
#pragma unroll
      for (int ks = 0; ks < 16; ks++) {
        acc0 = __builtin_amdgcn_mfma_f32_16x16x32_bf16(Af[ks], Bf[0][ks], acc0, 0, 0, 0);
        acc1 = __builtin_amdgcn_mfma_f32_16x16x32_bf16(Af[ks], Bf[1][ks], acc1, 0, 0, 0);
        acc2 = __builtin_amdgcn_mfma_f32_16x16x32_bf16(Af[ks], Bf[2][ks], acc2, 0, 0, 0);
      }
    }

    // gates (fp32). hm includes b_r here; xm already includes b_i.
#pragma unroll
    for (int i = 0; i < 4; i++) {
      float hz = acc0[i] + br0;
      float hr = acc1[i] + br1;
      float hh = acc2[i] + br2;
      float xz = bf2f(xc[0][i]);
      float xr = bf2f(xc[1][i]);
      float xh = bf2f(xc[2][i]);
      float z = 1.f / (1.f + __expf(-(xz + hz)));
      float r = 1.f / (1.f + __expf(-(xr + hr)));
      float y = xh + r * hh;
      float ay = fabsf(y);
      float e = __expf(-2.f * ay);
      float ca = (1.f - e) / (1.f + e);          // |tanh|
      ca = (y < 0.f) ? -ca : ca;
      hreg[i] = z * hreg[i] + (1.f - z) * ca;
    }

    if (t < 1023) {
      unsigned short* hw = h_bf + (t & 1) * (64 * 512);
#pragma unroll
      for (int i = 0; i < 4; i++) {
        int batch = wave * 16 + krow * 4 + i;
        // pack (unit u0+col, u0+col+1) into one 32-bit agent-scope atomic store
        float other = __shfl_xor(hreg[i], 1);
        if ((col & 1) == 0) {
          unsigned w = (unsigned)f2bf(hreg[i]) | ((unsigned)f2bf(other) << 16);
          unsigned* p = (unsigned*)(hw + (size_t)batch * 512 + u0 + col);
          __hip_atomic_store(p, w, __ATOMIC_RELAXED, __HIP_MEMORY_SCOPE_AGENT);
        }
      }
      // all 4 waves' stores are vmcnt-drained before s_barrier (compiler-enforced),
      // so the single release below publishes the whole block's slice.
      __syncthreads();
      if (tid == 0) {
        __hip_atomic_store(&flags[blk], (unsigned)(t + 1),
                           __ATOMIC_RELEASE, __HIP_MEMORY_SCOPE_AGENT);
      }
    }

#pragma unroll
    for (int g = 0; g < 3; g++)
#pragma unroll
      for (int i = 0; i < 4; i++) xc[g][i] = xn[g][i];
  }

#pragma unroll
  for (int i = 0; i < 4; i++) {
    int batch = wave * 16 + krow * 4 + i;
    out[(size_t)batch * 512 + u0 + col] = hreg[i];
  }
}

// ---------------- launch ----------------
extern "C" void kernel_launch(void* const* d_in, const int* in_sizes, int n_in,
                              void* d_out, int out_size, void* d_ws, size_t ws_size,
                              hipStream_t stream) {
  const float* x = (const float*)d_in[0];       // [64][1024][512]
  const float* W = (const float*)d_in[1];       // [512][1536]
  const float* R = (const float*)d_in[2];       // [512][1536]
  const float* bias = (const float*)d_in[3];    // [2][1536]
  float* out = (float*)d_out;

  char* ws = (char*)d_ws;
  unsigned int* flags = (unsigned int*)(ws + 0);
  unsigned short* h_bf = (unsigned short*)(ws + 4096);
  unsigned short* Wt = (unsigned short*)(ws + 135168);
  unsigned short* Rt = (unsigned short*)(ws + 1708032);
  unsigned short* XM = (unsigned short*)(ws + 3280896);

  hipMemsetAsync(flags, 0, 4096, stream);

  transpose_cast<<<dim3(48, 16), dim3(32, 8), 0, stream>>>(W, Wt, 512, 1536);
  transpose_cast<<<dim3(48, 16), dim3(32, 8), 0, stream>>>(R, Rt, 512, 1536);
  xm_gemm<<<dim3(512, 12), dim3(256), 0, stream>>>(x, Wt, bias, XM);
  gru_rec<<<dim3(32), dim3(256), 0, stream>>>(Rt, XM, bias, h_bf, flags, out);
}

// Round 5
// 6433.620 us; speedup vs baseline: 1.1669x; 1.1669x over previous
//
#include <hip/hip_runtime.h>
#include <hip/hip_bf16.h>

// GRU B=64 T=1024 D=U=512, reset_after=true. fp32 in/out, bf16 MFMA internally.
//
// ws layout (bytes):
//   [0,128)                  flags[32]  (one 128B line; memset each launch)
//   [4096, +131072)          h broadcast, bf16, double buffered [2][64][512]
//   [135168, +1572864)       Wt  bf16 [1536][512]  (kernel^T)
//   [1708032, +1572864)      Rt  bf16 [1536][512]  (recurrent_kernel^T)
//   [3280896, +201326592)    XM  bf16 [T*64][1536] (x@W + b_i), row = t*64+b

typedef __attribute__((ext_vector_type(8))) short short8;
typedef __attribute__((ext_vector_type(4))) float f32x4;

__device__ __forceinline__ unsigned short f2bf(float f) {
  unsigned u = __float_as_uint(f);
  u += 0x7FFFu + ((u >> 16) & 1u);   // RNE
  return (unsigned short)(u >> 16);
}
__device__ __forceinline__ float bf2f(unsigned short s) {
  return __uint_as_float(((unsigned)s) << 16);
}

// ---------------- Phase 0: transpose fp32 [R][C] -> bf16 [C][R] ----------------
__global__ void transpose_cast(const float* __restrict__ src,
                               unsigned short* __restrict__ dst,
                               int R, int C) {
  __shared__ float tile[32][33];
  int c0 = blockIdx.x * 32, r0 = blockIdx.y * 32;
  int tx = threadIdx.x, ty = threadIdx.y;
#pragma unroll
  for (int i = 0; i < 4; i++) {
    tile[ty + i * 8][tx] = src[(size_t)(r0 + ty + i * 8) * C + c0 + tx];
  }
  __syncthreads();
#pragma unroll
  for (int i = 0; i < 4; i++) {
    dst[(size_t)(c0 + ty + i * 8) * R + r0 + tx] = f2bf(tile[tx][ty + i * 8]);
  }
}

// ---------------- Phase 1: XM = x @ W + b_i  (bf16 out) ----------------
// M=65536 (row = t*64+b), N=1536, K=512. Tiles 128x128x64, 4 waves.
__global__ __launch_bounds__(256) void xm_gemm(const float* __restrict__ x,
                                               const unsigned short* __restrict__ Wt,
                                               const float* __restrict__ bias,
                                               unsigned short* __restrict__ XM) {
  __shared__ unsigned short As[128][72];
  __shared__ unsigned short Bs[128][72];
  const int tid = threadIdx.x;
  const int bm = blockIdx.x;   // 512
  const int bn = blockIdx.y;   // 12
  const int wave = tid >> 6, lane = tid & 63;
  const int moff = (wave & 1) * 64, noff = (wave >> 1) * 64;

  f32x4 acc[4][4];
#pragma unroll
  for (int mt = 0; mt < 4; mt++)
#pragma unroll
    for (int nt = 0; nt < 4; nt++) acc[mt][nt] = (f32x4){0.f, 0.f, 0.f, 0.f};

  const int r = tid >> 1;
  const int kb = (tid & 1) * 32;
  const int rg = bm * 128 + r;
  const int bb = rg & 63, tt = rg >> 6;

  for (int k0 = 0; k0 < 512; k0 += 64) {
    // A fill: 128 rows x 64 k fp32 -> bf16
    const f32x4* xp4 = (const f32x4*)(x + ((size_t)bb * 1024 + tt) * 512 + k0 + kb);
#pragma unroll
    for (int j = 0; j < 4; j++) {
      f32x4 lo = xp4[2 * j];
      f32x4 hi = xp4[2 * j + 1];
      union { unsigned short us[8]; short8 v; } u;
      u.us[0] = f2bf(lo[0]); u.us[1] = f2bf(lo[1]); u.us[2] = f2bf(lo[2]); u.us[3] = f2bf(lo[3]);
      u.us[4] = f2bf(hi[0]); u.us[5] = f2bf(hi[1]); u.us[6] = f2bf(hi[2]); u.us[7] = f2bf(hi[3]);
      *(short8*)&As[r][kb + j * 8] = u.v;
    }
    // B fill: Wt rows n, k-contiguous bf16
    const short8* wp8 = (const short8*)(Wt + (size_t)(bn * 128 + r) * 512 + k0 + kb);
#pragma unroll
    for (int j = 0; j < 4; j++) *(short8*)&Bs[r][kb + j * 8] = wp8[j];
    __syncthreads();

#pragma unroll
    for (int kk = 0; kk < 2; kk++) {
      short8 a[4], b[4];
#pragma unroll
      for (int mt = 0; mt < 4; mt++)
        a[mt] = *(const short8*)&As[moff + mt * 16 + (lane & 15)][kk * 32 + (lane >> 4) * 8];
#pragma unroll
      for (int nt = 0; nt < 4; nt++)
        b[nt] = *(const short8*)&Bs[noff + nt * 16 + (lane & 15)][kk * 32 + (lane >> 4) * 8];
#pragma unroll
      for (int mt = 0; mt < 4; mt++)
#pragma unroll
        for (int nt = 0; nt < 4; nt++)
          acc[mt][nt] = __builtin_amdgcn_mfma_f32_16x16x32_bf16(a[mt], b[nt], acc[mt][nt], 0, 0, 0);
    }
    __syncthreads();
  }

#pragma unroll
  for (int nt = 0; nt < 4; nt++) {
    const int cg = bn * 128 + noff + nt * 16 + (lane & 15);
    const float bi = bias[cg];
#pragma unroll
    for (int mt = 0; mt < 4; mt++) {
      const int rg2 = bm * 128 + moff + mt * 16 + (lane >> 4) * 4;
#pragma unroll
      for (int i = 0; i < 4; i++)
        XM[(size_t)(rg2 + i) * 1536 + cg] = f2bf(acc[mt][nt][i] + bi);
    }
  }
}

// ---------------- Phase 2: sequential recurrence, persistent grid ----------------
// 32 blocks x 256 threads. Block owns 16 units (48 R^T rows in VGPRs).
// h broadcast: double-buffered global bf16, relaxed agent atomics (MALL).
// Rendezvous per step:
//   all waves: h-stores (relaxed, distinct addresses)
//   explicit vmcnt(0) + __syncthreads  -> all block's stores MALL-acked
//   tid0: relaxed store flags[blk] = t+1   (32 parallel arrivals, no RMW)
//   wave0 only polls the 128B flag line; __syncthreads releases the block.
__global__ __launch_bounds__(256, 1) void gru_rec(const unsigned short* __restrict__ Rt,
                                                  const unsigned short* __restrict__ XM,
                                                  const float* __restrict__ bias,
                                                  unsigned short* h_bf,
                                                  unsigned int* flags,
                                                  float* __restrict__ out) {
  const int tid = threadIdx.x;
  const int lane = tid & 63;
  const int wave = tid >> 6;          // 0..3 -> batches wave*16..+15
  const int blk = blockIdx.x;         // 0..31 -> units blk*16..+15
  const int u0 = blk * 16;
  const int col = lane & 15;
  const int krow = lane >> 4;         // 0..3

  // B fragments: Rt[g*512+u0+col][k], k = ks*32 + krow*8 + j
  short8 Bf[3][16];
#pragma unroll
  for (int g = 0; g < 3; g++)
#pragma unroll
    for (int ks = 0; ks < 16; ks++)
      Bf[g][ks] = *(const short8*)(Rt + (size_t)(g * 512 + u0 + col) * 512 + ks * 32 + krow * 8);

  const float br0 = bias[1536 + 0 * 512 + u0 + col];
  const float br1 = bias[1536 + 1 * 512 + u0 + col];
  const float br2 = bias[1536 + 2 * 512 + u0 + col];

  float hreg[4] = {0.f, 0.f, 0.f, 0.f};   // own (batch,unit) state, fp32

  unsigned short xc[3][4], xn[3][4];
#pragma unroll
  for (int g = 0; g < 3; g++)
#pragma unroll
    for (int i = 0; i < 4; i++) {
      int batch = wave * 16 + krow * 4 + i;
      xc[g][i] = XM[(size_t)batch * 1536 + g * 512 + u0 + col];
    }

#pragma unroll 1
  for (int t = 0; t < 1024; ++t) {
    f32x4 acc0 = (f32x4){0.f, 0.f, 0.f, 0.f};
    f32x4 acc1 = acc0, acc2 = acc0;
    const int tn = (t < 1023) ? t + 1 : 1023;

    if (t > 0) {
      // ---- detect: wave0 polls the single 128B flag line ----
      if (wave == 0) {
        const unsigned tgt = (unsigned)t;
        for (;;) {
          unsigned v = (lane < 32)
              ? __hip_atomic_load(&flags[lane], __ATOMIC_RELAXED, __HIP_MEMORY_SCOPE_AGENT)
              : tgt;
          if (__all((int)(v >= tgt))) break;
          __builtin_amdgcn_s_sleep(1);
        }
      }
      __syncthreads();

      // ---- h loads first (MFMA then waits vmcnt(12), not a full drain) ----
      const unsigned short* hb = h_bf + ((t + 1) & 1) * (64 * 512);  // state from t-1
      const unsigned short* hp = hb + (size_t)(wave * 16 + col) * 512 + krow * 8;
      short8 Af[16];
#pragma unroll
      for (int ks = 0; ks < 16; ks++) {
        union { unsigned long long q[2]; short8 v; } u;
        const unsigned long long* p = (const unsigned long long*)(hp + ks * 32);
        u.q[0] = __hip_atomic_load(p, __ATOMIC_RELAXED, __HIP_MEMORY_SCOPE_AGENT);
        u.q[1] = __hip_atomic_load(p + 1, __ATOMIC_RELAXED, __HIP_MEMORY_SCOPE_AGENT);
        Af[ks] = u.v;
      }

      // ---- XM prefetch for t+1, issued after the h loads ----
#pragma unroll
      for (int g = 0; g < 3; g++)
#pragma unroll
        for (int i = 0; i < 4; i++) {
          int batch = wave * 16 + krow * 4 + i;
          xn[g][i] = XM[(size_t)(tn * 64 + batch) * 1536 + g * 512 + u0 + col];
        }

#pragma unroll
      for (int ks = 0; ks < 16; ks++) {
        acc0 = __builtin_amdgcn_mfma_f32_16x16x32_bf16(Af[ks], Bf[0][ks], acc0, 0, 0, 0);
        acc1 = __builtin_amdgcn_mfma_f32_16x16x32_bf16(Af[ks], Bf[1][ks], acc1, 0, 0, 0);
        acc2 = __builtin_amdgcn_mfma_f32_16x16x32_bf16(Af[ks], Bf[2][ks], acc2, 0, 0, 0);
      }
    } else {
      // t == 0: no h yet; just prefetch XM for t=1
#pragma unroll
      for (int g = 0; g < 3; g++)
#pragma unroll
        for (int i = 0; i < 4; i++) {
          int batch = wave * 16 + krow * 4 + i;
          xn[g][i] = XM[(size_t)(tn * 64 + batch) * 1536 + g * 512 + u0 + col];
        }
    }

    // gates (fp32). hm includes b_r here; xm already includes b_i.
#pragma unroll
    for (int i = 0; i < 4; i++) {
      float hz = acc0[i] + br0;
      float hr = acc1[i] + br1;
      float hh = acc2[i] + br2;
      float xz = bf2f(xc[0][i]);
      float xr = bf2f(xc[1][i]);
      float xh = bf2f(xc[2][i]);
      float z = 1.f / (1.f + __expf(-(xz + hz)));
      float r = 1.f / (1.f + __expf(-(xr + hr)));
      float y = xh + r * hh;
      float ay = fabsf(y);
      float e = __expf(-2.f * ay);
      float ca = (1.f - e) / (1.f + e);          // |tanh|
      ca = (y < 0.f) ? -ca : ca;
      hreg[i] = z * hreg[i] + (1.f - z) * ca;
    }

    if (t < 1023) {
      unsigned short* hw = h_bf + (t & 1) * (64 * 512);
#pragma unroll
      for (int i = 0; i < 4; i++) {
        int batch = wave * 16 + krow * 4 + i;
        // pack (unit u0+col, u0+col+1) into one 32-bit agent-scope atomic store
        float other = __shfl_xor(hreg[i], 1);
        if ((col & 1) == 0) {
          unsigned w = (unsigned)f2bf(hreg[i]) | ((unsigned)f2bf(other) << 16);
          unsigned* p = (unsigned*)(hw + (size_t)batch * 512 + u0 + col);
          __hip_atomic_store(p, w, __ATOMIC_RELAXED, __HIP_MEMORY_SCOPE_AGENT);
        }
      }
      // explicit drain: every wave's h-stores MALL-acked before it arrives at
      // the barrier, so after the barrier the whole block's slice is visible.
      asm volatile("s_waitcnt vmcnt(0)" ::: "memory");
      __syncthreads();
      if (tid == 0) {
        __hip_atomic_store(&flags[blk], (unsigned)(t + 1),
                           __ATOMIC_RELAXED, __HIP_MEMORY_SCOPE_AGENT);
      }
    }

#pragma unroll
    for (int g = 0; g < 3; g++)
#pragma unroll
      for (int i = 0; i < 4; i++) xc[g][i] = xn[g][i];
  }

#pragma unroll
  for (int i = 0; i < 4; i++) {
    int batch = wave * 16 + krow * 4 + i;
    out[(size_t)batch * 512 + u0 + col] = hreg[i];
  }
}

// ---------------- launch ----------------
extern "C" void kernel_launch(void* const* d_in, const int* in_sizes, int n_in,
                              void* d_out, int out_size, void* d_ws, size_t ws_size,
                              hipStream_t stream) {
  const float* x = (const float*)d_in[0];       // [64][1024][512]
  const float* W = (const float*)d_in[1];       // [512][1536]
  const float* R = (const float*)d_in[2];       // [512][1536]
  const float* bias = (const float*)d_in[3];    // [2][1536]
  float* out = (float*)d_out;

  char* ws = (char*)d_ws;
  unsigned int* flags = (unsigned int*)(ws + 0);
  unsigned short* h_bf = (unsigned short*)(ws + 4096);
  unsigned short* Wt = (unsigned short*)(ws + 135168);
  unsigned short* Rt = (unsigned short*)(ws + 1708032);
  unsigned short* XM = (unsigned short*)(ws + 3280896);

  hipMemsetAsync(flags, 0, 4096, stream);

  transpose_cast<<<dim3(48, 16), dim3(32, 8), 0, stream>>>(W, Wt, 512, 1536);
  transpose_cast<<<dim3(48, 16), dim3(32, 8), 0, stream>>>(R, Rt, 512, 1536);
  xm_gemm<<<dim3(512, 12), dim3(256), 0, stream>>>(x, Wt, bias, XM);
  gru_rec<<<dim3(32), dim3(256), 0, stream>>>(Rt, XM, bias, h_bf, flags, out);
}